// Round 1
// baseline (255.026 us; speedup 1.0000x reference)
//
#include <hip/hip_runtime.h>
#include <stdint.h>

#define EPS_F 1e-7f

typedef __bf16 bf16x8 __attribute__((ext_vector_type(8)));
typedef float f32x4 __attribute__((ext_vector_type(4)));

__device__ __forceinline__ unsigned f2bf_u(float f) {
  unsigned u = __float_as_uint(f);
  return (u + 0x7fffu + ((u >> 16) & 1u)) >> 16;  // RNE
}
__device__ __forceinline__ unsigned pack2(float a, float b) {
  return f2bf_u(a) | (f2bf_u(b) << 16);
}
__device__ __forceinline__ bf16x8 as_bf16x8(uint4 v) {
  union { uint4 u; bf16x8 b; } x; x.u = v; return x.b;
}
__device__ __forceinline__ void gld16(const void* g, void* l) {
  // async global->LDS, 16B per lane; LDS dest = wave-uniform base + lane*16
  __builtin_amdgcn_global_load_lds(
      (__attribute__((address_space(1))) void*)g,
      (__attribute__((address_space(3))) void*)l, 16, 0, 0);
}

// ---------------------------------------------------------------------------
// prep_B: prototypes fp32 (2048x512, row-major) -> bf16, pre-swizzled into
// MFMA B-fragment order.  Chunk id = ((ct*16 + kstep)*8 + nfrag)*64 + lane,
// holding 8 contiguous k elements for (n = nfrag*16 + (lane&15),
// k = kstep*32 + (lane>>4)*8 + j).  One thread per 16B chunk.
// ---------------------------------------------------------------------------
__global__ __launch_bounds__(256) void prep_B_kernel(
    const float* __restrict__ protos, uint16_t* __restrict__ wsB) {
  int tid  = blockIdx.x * 256 + threadIdx.x;  // [0, 131072)
  int lane = tid & 63;
  int nf   = (tid >> 6) & 7;
  int ks   = (tid >> 9) & 15;
  int ct   = tid >> 13;
  int c    = ct * 128 + nf * 16 + (lane & 15);
  int k0   = ks * 32 + (lane >> 4) * 8;
  const float4* p = (const float4*)(protos + c * 512 + k0);
  float4 f0 = p[0], f1 = p[1];
  uint4 o;
  o.x = pack2(f0.x, f0.y); o.y = pack2(f0.z, f0.w);
  o.z = pack2(f1.x, f1.y); o.w = pack2(f1.z, f1.w);
  ((uint4*)wsB)[tid] = o;  // coalesced 16B stores
}

// ---------------------------------------------------------------------------
// prep_y2: per-prototype squared norm (fp32, from fp32 input). Block 0 also
// zeroes the output accumulator (d_out is poisoned before every launch).
// ---------------------------------------------------------------------------
__global__ __launch_bounds__(64) void prep_y2_kernel(
    const float* __restrict__ protos, float* __restrict__ y2,
    float* __restrict__ out) {
  int c    = blockIdx.x;
  int lane = threadIdx.x;
  const float4* p = (const float4*)(protos + c * 512 + lane * 8);
  float4 f0 = p[0], f1 = p[1];
  float s = f0.x*f0.x + f0.y*f0.y + f0.z*f0.z + f0.w*f0.w
          + f1.x*f1.x + f1.y*f1.y + f1.z*f1.z + f1.w*f1.w;
#pragma unroll
  for (int off = 32; off > 0; off >>= 1) s += __shfl_xor(s, off, 64);
  if (lane == 0) {
    y2[c] = s;
    if (blockIdx.x == 0) out[0] = 0.f;
  }
}

// ---------------------------------------------------------------------------
// gemm_min: one block per 128 z-rows (grid=256 = 1 block/CU).
//  - stage A fp32->bf16 swizzled into 128KB LDS ONCE (plus x2 per row)
//  - sweep 16 c-tiles x 16 k-steps, B tile (8KB) double-buffered via
//    global_load_lds from the pre-swizzled ws image
//  - wave-tile 64x64 (4 waves), 16x16x32 bf16 MFMA
//  - fused epilogue: per-row running min of t = sqdist/max(denom,EPS),
//    then acosh/relu/mean with one atomicAdd per block.
// ---------------------------------------------------------------------------
__global__ __launch_bounds__(256) void gemm_min_kernel(
    const float* __restrict__ z, const uint16_t* __restrict__ wsB,
    const float* __restrict__ y2, const float* __restrict__ marg,
    float* __restrict__ out) {
  __shared__ uint16_t As[16 * 8 * 64 * 8];  // 128 KB, fragment-swizzled
  __shared__ uint16_t Bb[2][4096];          // 2 x 8 KB
  __shared__ float x2s[128];
  __shared__ float minbuf[128][2];
  __shared__ float redbuf[2];

  const int tid  = threadIdx.x;
  const int lane = tid & 63;
  const int w    = tid >> 6;   // wave id 0..3
  const int wm   = w >> 1;     // row half
  const int wn   = w & 1;      // col half
  const int quad = lane >> 4;
  const int l15  = lane & 15;

  // ---- A staging: 128x512 fp32 -> bf16 swizzled; x2 per row ----
  const float* Ag = z + (size_t)blockIdx.x * (128 * 512);
  for (int i = 0; i < 32; ++i) {
    int ci  = i * 256 + tid;        // one wave <-> one row per i
    int row = ci >> 6;
    int oct = ci & 63;
    const float4* p = (const float4*)(Ag + row * 512 + oct * 8);
    float4 f0 = p[0], f1 = p[1];
    float s = f0.x*f0.x + f0.y*f0.y + f0.z*f0.z + f0.w*f0.w
            + f1.x*f1.x + f1.y*f1.y + f1.z*f1.z + f1.w*f1.w;
#pragma unroll
    for (int off = 32; off > 0; off >>= 1) s += __shfl_xor(s, off, 64);
    if (lane == 0) x2s[row] = s;    // each (i,w) owns a distinct row
    int ks = oct >> 2, q = oct & 3;
    int chunk = (ks * 8 + (row >> 4)) * 64 + q * 16 + (row & 15);
    uint4 o;
    o.x = pack2(f0.x, f0.y); o.y = pack2(f0.z, f0.w);
    o.z = pack2(f1.x, f1.y); o.w = pack2(f1.z, f1.w);
    ((uint4*)As)[chunk] = o;
  }

  f32x4 acc[4][4];
  float tmin[4][4];
#pragma unroll
  for (int a = 0; a < 4; ++a)
#pragma unroll
    for (int r = 0; r < 4; ++r) tmin[a][r] = 3.4e38f;

  // prefetch B tile 0 (barrier at loop top makes it visible)
  {
    const uint16_t* src = wsB + (size_t)w * 1024 + lane * 8;
    uint16_t* dst = &Bb[0][w * 1024];
    gld16(src, dst);
    gld16(src + 512, dst + 512);
  }

  for (int ct = 0; ct < 16; ++ct) {
#pragma unroll
    for (int a = 0; a < 4; ++a)
#pragma unroll
      for (int b = 0; b < 4; ++b) {
        f32x4 zz = {0.f, 0.f, 0.f, 0.f};
        acc[a][b] = zz;
      }

    for (int kk = 0; kk < 16; ++kk) {
      const int idx = ct * 16 + kk;
      __syncthreads();  // stage(idx) visible; readers of other buf done
      if (idx + 1 < 256) {
        const uint16_t* src = wsB + (size_t)(idx + 1) * 4096 + w * 1024 + lane * 8;
        uint16_t* dst = &Bb[(idx + 1) & 1][w * 1024];
        gld16(src, dst);
        gld16(src + 512, dst + 512);
      }
      bf16x8 af[4], bfr[4];
      const uint4* Ap = (const uint4*)As;
      const uint4* Bp = (const uint4*)(Bb[idx & 1]);
#pragma unroll
      for (int a = 0; a < 4; ++a)
        af[a] = as_bf16x8(Ap[(kk * 8 + wm * 4 + a) * 64 + lane]);
#pragma unroll
      for (int b = 0; b < 4; ++b)
        bfr[b] = as_bf16x8(Bp[(wn * 4 + b) * 64 + lane]);
#pragma unroll
      for (int a = 0; a < 4; ++a)
#pragma unroll
        for (int b = 0; b < 4; ++b)
          acc[a][b] = __builtin_amdgcn_mfma_f32_16x16x32_bf16(
              af[a], bfr[b], acc[a][b], 0, 0, 0);
    }

    // fused epilogue: running min of t over this c-tile's 128 columns
    float y2v[4], omy[4];
#pragma unroll
    for (int b = 0; b < 4; ++b) {
      y2v[b] = y2[ct * 128 + (wn * 4 + b) * 16 + l15];
      omy[b] = 1.f - y2v[b];
    }
#pragma unroll
    for (int a = 0; a < 4; ++a) {
#pragma unroll
      for (int r = 0; r < 4; ++r) {
        int rowl = wm * 64 + a * 16 + quad * 4 + r;  // C/D: row = quad*4+reg
        float x2v = x2s[rowl];
        float omx = 1.f - x2v;
#pragma unroll
        for (int b = 0; b < 4; ++b) {
          float sq  = fmaxf(x2v + y2v[b] - 2.f * acc[a][b][r], 0.f);
          float den = fmaxf(omx * omy[b], EPS_F);
          tmin[a][r] = fminf(tmin[a][r], sq / den);
        }
      }
    }
  }

  // min across the 16 lanes of each column group (same row)
#pragma unroll
  for (int a = 0; a < 4; ++a) {
#pragma unroll
    for (int r = 0; r < 4; ++r) {
      float v = tmin[a][r];
#pragma unroll
      for (int off = 1; off <= 8; off <<= 1) v = fminf(v, __shfl_xor(v, off, 64));
      if (l15 == 0) minbuf[wm * 64 + a * 16 + quad * 4 + r][wn] = v;
    }
  }
  __syncthreads();

  float contrib = 0.f;
  if (tid < 128) {
    float tm  = fminf(minbuf[tid][0], minbuf[tid][1]);
    float arg = fmaxf(fmaf(2.f, tm, 1.f), 1.f + EPS_F);
    float d   = acoshf(arg);
    contrib = fmaxf(marg[0] - d, 0.f);
  }
#pragma unroll
  for (int off = 32; off > 0; off >>= 1) contrib += __shfl_xor(contrib, off, 64);
  if (tid < 128 && lane == 0) redbuf[w] = contrib;
  __syncthreads();
  if (tid == 0) atomicAdd(out, (redbuf[0] + redbuf[1]) * (1.0f / 32768.f));
}

// ---------------------------------------------------------------------------
extern "C" void kernel_launch(void* const* d_in, const int* in_sizes, int n_in,
                              void* d_out, int out_size, void* d_ws, size_t ws_size,
                              hipStream_t stream) {
  const float* z      = (const float*)d_in[0];  // 32768 x 512 fp32
  const float* protos = (const float*)d_in[1];  // 2048 x 512 fp32
  const float* marg   = (const float*)d_in[2];  // scalar
  float* out = (float*)d_out;
  uint16_t* wsB = (uint16_t*)d_ws;                                   // 2 MB
  float* y2 = (float*)((char*)d_ws + (size_t)2 * 1024 * 1024);       // 8 KB

  prep_B_kernel<<<512, 256, 0, stream>>>(protos, wsB);
  prep_y2_kernel<<<2048, 64, 0, stream>>>(protos, y2, out);
  gemm_min_kernel<<<256, 256, 0, stream>>>(z, wsB, y2, marg, out);
}

// Round 2
// 237.026 us; speedup vs baseline: 1.0759x; 1.0759x over previous
//
#include <hip/hip_runtime.h>
#include <stdint.h>

#define EPS_F 1e-7f

typedef __bf16 bf16x8 __attribute__((ext_vector_type(8)));
typedef float f32x4 __attribute__((ext_vector_type(4)));

__device__ __forceinline__ unsigned f2bf_u(float f) {
  unsigned u = __float_as_uint(f);
  return (u + 0x7fffu + ((u >> 16) & 1u)) >> 16;  // RNE
}
__device__ __forceinline__ unsigned pack2(float a, float b) {
  return f2bf_u(a) | (f2bf_u(b) << 16);
}
__device__ __forceinline__ bf16x8 as_bf16x8(uint4 v) {
  union { uint4 u; bf16x8 b; } x; x.u = v; return x.b;
}

// ---------------------------------------------------------------------------
// prep: (1) prototypes fp32 -> bf16 pre-swizzled into MFMA B-fragment order:
//       chunk id = ((ct*16 + kstep)*8 + nfrag)*64 + lane holds 8 contiguous k
//       for (n = nfrag*16 + (lane&15), k = kstep*32 + (lane>>4)*8 + j).
//       (2) y2[c] = ||proto_c||^2 in fp32.  (3) zero the output accumulator.
// ---------------------------------------------------------------------------
__global__ __launch_bounds__(256) void prep_kernel(
    const float* __restrict__ protos, uint16_t* __restrict__ wsB,
    float* __restrict__ y2, float* __restrict__ out) {
  int tid = blockIdx.x * 256 + threadIdx.x;  // [0, 131072)
  {
    int lane = tid & 63;
    int nf   = (tid >> 6) & 7;
    int ks   = (tid >> 9) & 15;
    int ct   = tid >> 13;
    int c    = ct * 128 + nf * 16 + (lane & 15);
    int k0   = ks * 32 + (lane >> 4) * 8;
    const float4* p = (const float4*)(protos + c * 512 + k0);
    float4 f0 = p[0], f1 = p[1];
    uint4 o;
    o.x = pack2(f0.x, f0.y); o.y = pack2(f0.z, f0.w);
    o.z = pack2(f1.x, f1.y); o.w = pack2(f1.z, f1.w);
    ((uint4*)wsB)[tid] = o;
  }
  {  // y2: one wave per prototype row, fp32-exact
    int lane = threadIdx.x & 63;
    int w    = threadIdx.x >> 6;
    int row  = blockIdx.x * 4 + w;
    const float4* p = (const float4*)(protos + row * 512 + lane * 8);
    float4 f0 = p[0], f1 = p[1];
    float s = f0.x*f0.x + f0.y*f0.y + f0.z*f0.z + f0.w*f0.w
            + f1.x*f1.x + f1.y*f1.y + f1.z*f1.z + f1.w*f1.w;
#pragma unroll
    for (int off = 32; off > 0; off >>= 1) s += __shfl_xor(s, off, 64);
    if (lane == 0) y2[row] = s;
  }
  if (blockIdx.x == 0 && threadIdx.x == 0) out[0] = 0.f;
}

// ---------------------------------------------------------------------------
// gemm_min: one block per 128 z-rows, grid=256 (1 block/CU).
//   - A (128x512) converted fp32->bf16 and staged ONCE into LDS in A-fragment
//     order (conflict-free contiguous 16B/lane writes); ONE barrier total.
//   - B fragments loaded straight from the L2-resident pre-swizzled wsB image
//     into registers, double-buffered one k-step ahead (no LDS, no barrier).
//   - wave-tile 64x64 (4 waves), 16 independent MFMAs per k-step: 256 cyc of
//     matrix pipe per step > ~200 cyc L2 latency -> loads fully hidden even
//     at 1 wave/SIMD.
//   - fused epilogue per c-tile: running min of t = sqdist/max(denom,EPS);
//     acosh/relu/mean at the end, one atomicAdd per block.
// ---------------------------------------------------------------------------
__global__ __launch_bounds__(256) void gemm_min_kernel(
    const float* __restrict__ z, const uint16_t* __restrict__ wsB,
    const float* __restrict__ y2, const float* __restrict__ marg,
    float* __restrict__ out) {
  __shared__ uint16_t As[16 * 8 * 64 * 8];  // 128 KB, fragment-swizzled
  __shared__ float x2s[128];
  __shared__ float minbuf[128][2];
  __shared__ float redbuf[2];

  const int tid  = threadIdx.x;
  const int lane = tid & 63;
  const int w    = tid >> 6;   // wave id 0..3
  const int wm   = w >> 1;     // row half
  const int wn   = w & 1;      // col half
  const int quad = lane >> 4;
  const int l15  = lane & 15;

  const float* Ag = z + (size_t)blockIdx.x * (128 * 512);

  // ---- A staging: chunk = i*256+tid (contiguous 16B/lane -> no conflicts).
  // chunk = ((kk*8 + rf)*64 + l6) holds row rf*16+(l6&15), k0 = kk*32+(l6>>4)*8
  for (int i = 0; i < 32; ++i) {
    int chunk = i * 256 + tid;
    int l6  = chunk & 63;
    int rf  = (chunk >> 6) & 7;
    int kk  = chunk >> 9;
    int row = rf * 16 + (l6 & 15);
    int k0  = kk * 32 + (l6 >> 4) * 8;
    const float4* p = (const float4*)(Ag + row * 512 + k0);
    float4 f0 = p[0], f1 = p[1];
    uint4 o;
    o.x = pack2(f0.x, f0.y); o.y = pack2(f0.z, f0.w);
    o.z = pack2(f1.x, f1.y); o.w = pack2(f1.z, f1.w);
    ((uint4*)As)[chunk] = o;
  }
  // ---- x2 per row, fp32-exact (re-reads slab; L2-hot). One wave per row.
  for (int j = 0; j < 32; ++j) {
    int row = w * 32 + j;
    const float4* p = (const float4*)(Ag + row * 512 + lane * 8);
    float4 f0 = p[0], f1 = p[1];
    float s = f0.x*f0.x + f0.y*f0.y + f0.z*f0.z + f0.w*f0.w
            + f1.x*f1.x + f1.y*f1.y + f1.z*f1.z + f1.w*f1.w;
#pragma unroll
    for (int off = 32; off > 0; off >>= 1) s += __shfl_xor(s, off, 64);
    if (lane == 0) x2s[row] = s;
  }
  __syncthreads();  // the ONLY pre-loop barrier

  const uint4* Ap = (const uint4*)As;
  const uint4* Bg = (const uint4*)wsB;

  f32x4 acc[4][4];
  float tmin[4][4];
#pragma unroll
  for (int a = 0; a < 4; ++a)
#pragma unroll
    for (int r = 0; r < 4; ++r) {
      tmin[a][r] = 3.4e38f;
      f32x4 zz = {0.f, 0.f, 0.f, 0.f};
      acc[a][r] = zz;
    }

  bf16x8 A0[4], B0[4], A1[4], B1[4];

  auto pf = [&](bf16x8 (&AF)[4], bf16x8 (&BF)[4], int nid) {
    int nkk = nid & 15;
#pragma unroll
    for (int a = 0; a < 4; ++a)
      AF[a] = as_bf16x8(Ap[(nkk * 8 + wm * 4 + a) * 64 + lane]);
#pragma unroll
    for (int b = 0; b < 4; ++b)
      BF[b] = as_bf16x8(Bg[((size_t)nid * 8 + wn * 4 + b) * 64 + lane]);
  };
  auto step = [&](bf16x8 (&AF)[4], bf16x8 (&BF)[4]) {
#pragma unroll
    for (int a = 0; a < 4; ++a)
#pragma unroll
      for (int b = 0; b < 4; ++b)
        acc[a][b] = __builtin_amdgcn_mfma_f32_16x16x32_bf16(
            AF[a], BF[b], acc[a][b], 0, 0, 0);
  };
  auto epilogue = [&](int ct) {
    float y2v[4], omy[4];
#pragma unroll
    for (int b = 0; b < 4; ++b) {
      y2v[b] = y2[ct * 128 + (wn * 4 + b) * 16 + l15];
      omy[b] = 1.f - y2v[b];
    }
#pragma unroll
    for (int a = 0; a < 4; ++a) {
#pragma unroll
      for (int r = 0; r < 4; ++r) {
        int rowl = wm * 64 + a * 16 + quad * 4 + r;  // C/D: row = quad*4+reg
        float x2v = x2s[rowl];
        float omx = 1.f - x2v;
#pragma unroll
        for (int b = 0; b < 4; ++b) {
          float sq  = fmaxf(x2v + y2v[b] - 2.f * acc[a][b][r], 0.f);
          float den = fmaxf(omx * omy[b], EPS_F);
          tmin[a][r] = fminf(tmin[a][r], sq / den);
        }
      }
    }
#pragma unroll
    for (int a = 0; a < 4; ++a)
#pragma unroll
      for (int b = 0; b < 4; ++b) {
        f32x4 zz = {0.f, 0.f, 0.f, 0.f};
        acc[a][b] = zz;
      }
  };

  pf(A0, B0, 0);
  for (int idx = 0; idx < 256; idx += 2) {
    pf(A1, B1, idx + 1);   // loads for odd step fly during even MFMAs
    step(A0, B0);
    if (idx + 2 < 256) pf(A0, B0, idx + 2);  // next ct's frags fly across epilogue
    step(A1, B1);
    if (((idx + 1) & 15) == 15) epilogue(idx >> 4);
  }

  // min across the 16 lanes of each column group (same row)
#pragma unroll
  for (int a = 0; a < 4; ++a) {
#pragma unroll
    for (int r = 0; r < 4; ++r) {
      float v = tmin[a][r];
#pragma unroll
      for (int off = 1; off <= 8; off <<= 1) v = fminf(v, __shfl_xor(v, off, 64));
      if (l15 == 0) minbuf[wm * 64 + a * 16 + quad * 4 + r][wn] = v;
    }
  }
  __syncthreads();

  float contrib = 0.f;
  if (tid < 128) {
    float tm  = fminf(minbuf[tid][0], minbuf[tid][1]);
    float arg = fmaxf(fmaf(2.f, tm, 1.f), 1.f + EPS_F);
    float d   = acoshf(arg);
    contrib = fmaxf(marg[0] - d, 0.f);
  }
#pragma unroll
  for (int off = 32; off > 0; off >>= 1) contrib += __shfl_xor(contrib, off, 64);
  if (tid < 128 && lane == 0) redbuf[w] = contrib;
  __syncthreads();
  if (tid == 0) atomicAdd(out, (redbuf[0] + redbuf[1]) * (1.0f / 32768.f));
}

// ---------------------------------------------------------------------------
extern "C" void kernel_launch(void* const* d_in, const int* in_sizes, int n_in,
                              void* d_out, int out_size, void* d_ws, size_t ws_size,
                              hipStream_t stream) {
  const float* z      = (const float*)d_in[0];  // 32768 x 512 fp32
  const float* protos = (const float*)d_in[1];  // 2048 x 512 fp32
  const float* marg   = (const float*)d_in[2];  // scalar
  float* out = (float*)d_out;
  uint16_t* wsB = (uint16_t*)d_ws;                                   // 2 MB
  float* y2 = (float*)((char*)d_ws + (size_t)2 * 1024 * 1024);       // 8 KB

  prep_kernel<<<512, 256, 0, stream>>>(protos, wsB, y2, out);
  gemm_min_kernel<<<256, 256, 0, stream>>>(z, wsB, y2, marg, out);
}